// Round 1
// baseline (928.144 us; speedup 1.0000x reference)
//
#include <hip/hip_runtime.h>

#define NNODES 50000
#define NEDGES 800000
#define NGRAPHS 64
#define INCH 128
#define HID 256
#define SCAN_B 512
#define SCAN_NB ((NNODES + SCAN_B - 1) / SCAN_B)   // 98

// ---------------- degree / dis ----------------
__global__ __launch_bounds__(256) void deg_kernel(const int* __restrict__ dst, int* __restrict__ deg) {
    int e = blockIdx.x * 256 + threadIdx.x;
    if (e < NEDGES) atomicAdd(&deg[dst[e]], 1);
}

__global__ __launch_bounds__(256) void dis_kernel(const int* __restrict__ deg, float* __restrict__ dis) {
    int i = blockIdx.x * 256 + threadIdx.x;
    if (i < NNODES) dis[i] = rsqrtf((float)deg[i] + 1.0f);
}

// ---------------- scan (row_ptr from deg) ----------------
__global__ __launch_bounds__(SCAN_B) void scan1(const int* __restrict__ deg, int* __restrict__ row_ptr,
                                                int* __restrict__ bsum) {
    __shared__ int s[SCAN_B];
    int t = threadIdx.x;
    int i = blockIdx.x * SCAN_B + t;
    int v = (i < NNODES) ? deg[i] : 0;
    s[t] = v;
    __syncthreads();
    for (int off = 1; off < SCAN_B; off <<= 1) {
        int x = (t >= off) ? s[t - off] : 0;
        __syncthreads();
        if (t >= off) s[t] += x;
        __syncthreads();
    }
    if (i < NNODES) row_ptr[i + 1] = s[t];
    if (t == SCAN_B - 1) bsum[blockIdx.x] = s[t];
}

__global__ __launch_bounds__(128) void scan2(int* __restrict__ bsum) {
    __shared__ int s[128];
    int t = threadIdx.x;
    int v = (t < SCAN_NB) ? bsum[t] : 0;
    s[t] = v;
    __syncthreads();
    for (int off = 1; off < 128; off <<= 1) {
        int x = (t >= off) ? s[t - off] : 0;
        __syncthreads();
        if (t >= off) s[t] += x;
        __syncthreads();
    }
    if (t < SCAN_NB) bsum[t] = s[t];
}

__global__ __launch_bounds__(SCAN_B) void scan3(int* __restrict__ row_ptr, const int* __restrict__ bsum) {
    int b = blockIdx.x, t = threadIdx.x;
    int i = b * SCAN_B + t;
    if (i == 0) row_ptr[0] = 0;
    if (i < NNODES && b > 0) row_ptr[i + 1] += bsum[b - 1];
}

// ---------------- CSR fill ----------------
__global__ __launch_bounds__(256) void fill_csr(const int* __restrict__ src, const int* __restrict__ dst,
                                                const float* __restrict__ dis, int* __restrict__ cursor,
                                                int* __restrict__ csr_src, float* __restrict__ csr_norm) {
    int e = blockIdx.x * 256 + threadIdx.x;
    if (e >= NEDGES) return;
    int s = src[e], d = dst[e];
    int pos = atomicAdd(&cursor[d], 1);
    csr_src[pos] = s;
    csr_norm[pos] = dis[s] * dis[d];
}

// ---------------- fp32 GEMM: C[M x N] = A[M x K] @ B[K x N] ----------------
__global__ __launch_bounds__(256) void gemm_f32(const float* __restrict__ A, const float* __restrict__ B,
                                                float* __restrict__ C, int M, int N, int K) {
    __shared__ float As[16][64];
    __shared__ float Bs[16][64];
    const int t = threadIdx.x;
    const int tx = t & 15, ty = t >> 4;
    const int row0 = blockIdx.y * 64, col0 = blockIdx.x * 64;
    const int ar = t >> 2, akq = (t & 3) << 2;
    const int bkr = t >> 4, bc = (t & 15) << 2;
    float acc[4][4] = {{0.f}};
    for (int k0 = 0; k0 < K; k0 += 16) {
        float4 av = make_float4(0.f, 0.f, 0.f, 0.f);
        int grow = row0 + ar;
        if (grow < M) av = *(const float4*)&A[(size_t)grow * K + k0 + akq];
        float4 bv = *(const float4*)&B[(size_t)(k0 + bkr) * N + col0 + bc];
        __syncthreads();
        As[akq + 0][ar] = av.x;
        As[akq + 1][ar] = av.y;
        As[akq + 2][ar] = av.z;
        As[akq + 3][ar] = av.w;
        *(float4*)&Bs[bkr][bc] = bv;
        __syncthreads();
#pragma unroll
        for (int kk = 0; kk < 16; ++kk) {
            float4 a4 = *(const float4*)&As[kk][ty << 2];
            float4 b4 = *(const float4*)&Bs[kk][tx << 2];
            float a[4] = {a4.x, a4.y, a4.z, a4.w};
            float b[4] = {b4.x, b4.y, b4.z, b4.w};
#pragma unroll
            for (int i = 0; i < 4; ++i)
#pragma unroll
                for (int j = 0; j < 4; ++j) acc[i][j] += a[i] * b[j];
        }
    }
#pragma unroll
    for (int i = 0; i < 4; ++i) {
        int grow = row0 + (ty << 2) + i;
        if (grow < M)
            *(float4*)&C[(size_t)grow * N + col0 + (tx << 2)] =
                make_float4(acc[i][0], acc[i][1], acc[i][2], acc[i][3]);
    }
}

// ---------------- aggregate: h_out = relu(sum_{j->i} norm*hW[j] + dis_i^2*hW[i] + b) ----------------
__global__ __launch_bounds__(256) void aggregate_k(const float4* __restrict__ hW, const int* __restrict__ row_ptr,
                                                   const int* __restrict__ csr_src,
                                                   const float* __restrict__ csr_norm,
                                                   const float* __restrict__ dis, const float* __restrict__ bias,
                                                   float4* __restrict__ h_out) {
    int node = blockIdx.x * 4 + (threadIdx.x >> 6);
    if (node >= NNODES) return;
    int lane = threadIdx.x & 63;
    float d = dis[node];
    float sw = d * d;
    float4 acc = hW[(size_t)node * 64 + lane];
    acc.x *= sw; acc.y *= sw; acc.z *= sw; acc.w *= sw;
    int e0 = row_ptr[node], e1 = row_ptr[node + 1];
    for (int e = e0; e < e1; ++e) {
        int s = csr_src[e];
        float w = csr_norm[e];
        float4 v = hW[(size_t)s * 64 + lane];
        acc.x += w * v.x; acc.y += w * v.y; acc.z += w * v.z; acc.w += w * v.w;
    }
    float4 b = ((const float4*)bias)[lane];
    acc.x = fmaxf(acc.x + b.x, 0.f);
    acc.y = fmaxf(acc.y + b.y, 0.f);
    acc.z = fmaxf(acc.z + b.z, 0.f);
    acc.w = fmaxf(acc.w + b.w, 0.f);
    h_out[(size_t)node * 64 + lane] = acc;
}

// ---------------- graph boundaries from sorted batch ----------------
__global__ __launch_bounds__(256) void graph_bounds(const int* __restrict__ batch, int* __restrict__ gstart) {
    int i = blockIdx.x * 256 + threadIdx.x;
    if (i >= NNODES) return;
    int b = batch[i];
    if (i == 0) {
        for (int g = 0; g <= b; ++g) gstart[g] = 0;
    } else {
        int pb = batch[i - 1];
        for (int g = pb + 1; g <= b; ++g) gstart[g] = i;
    }
    if (i == NNODES - 1) {
        for (int g = b + 1; g <= NGRAPHS; ++g) gstart[g] = NNODES;
    }
}

// ---------------- mean pool + concat hlr/std ----------------
__global__ __launch_bounds__(HID) void pool_k(const float* __restrict__ h, const int* __restrict__ gstart,
                                              const float* __restrict__ hlr, const float* __restrict__ stdv,
                                              float* __restrict__ z) {
    int g = blockIdx.x;
    int t = threadIdx.x;
    int n0 = gstart[g], n1 = gstart[g + 1];
    float acc = 0.f;
    for (int n = n0; n < n1; ++n) acc += h[(size_t)n * HID + t];
    float cnt = (float)max(n1 - n0, 1);
    z[g * (HID + 2) + t] = acc / cnt;
    if (t == 0) {
        z[g * (HID + 2) + HID] = hlr[g];
        z[g * (HID + 2) + HID + 1] = stdv[g];
    }
}

// ---------------- FC head: relu(z @ fcW0 + fcb0) @ fcW1 + fcb1 ----------------
__global__ __launch_bounds__(HID) void fc_k(const float* __restrict__ z, const float* __restrict__ fcW0,
                                            const float* __restrict__ fcb0, const float* __restrict__ fcW1,
                                            const float* __restrict__ fcb1, float* __restrict__ out) {
    __shared__ float zs[HID + 2];
    __shared__ float z2[HID];
    int g = blockIdx.x;
    int t = threadIdx.x;
    zs[t] = z[g * (HID + 2) + t];
    if (t < 2) zs[HID + t] = z[g * (HID + 2) + HID + t];
    __syncthreads();
    float acc = fcb0[t];
    for (int k = 0; k < HID + 2; ++k) acc += zs[k] * fcW0[k * HID + t];
    z2[t] = fmaxf(acc, 0.f);
    __syncthreads();
    if (t < INCH) {
        float acc2 = fcb1[t];
        for (int k = 0; k < HID; ++k) acc2 += z2[k] * fcW1[k * INCH + t];
        out[g * INCH + t] = acc2;
    }
}

extern "C" void kernel_launch(void* const* d_in, const int* in_sizes, int n_in,
                              void* d_out, int out_size, void* d_ws, size_t ws_size,
                              hipStream_t stream) {
    const float* x = (const float*)d_in[0];
    const int* ei = (const int*)d_in[1];
    const int* src = ei;
    const int* dst = ei + NEDGES;
    const int* batch = (const int*)d_in[2];
    const float* hlr = (const float*)d_in[3];
    const float* stdv = (const float*)d_in[4];
    const float* W0 = (const float*)d_in[5];
    const float* b0 = (const float*)d_in[6];
    const float* W1 = (const float*)d_in[7];
    const float* b1 = (const float*)d_in[8];
    const float* W2 = (const float*)d_in[9];
    const float* b2 = (const float*)d_in[10];
    const float* fcW0 = (const float*)d_in[11];
    const float* fcb0 = (const float*)d_in[12];
    const float* fcW1 = (const float*)d_in[13];
    const float* fcb1 = (const float*)d_in[14];
    float* out = (float*)d_out;

    char* p = (char*)d_ws;
    auto alloc = [&](size_t bytes) -> char* {
        char* r = p;
        p += (bytes + 255) & ~(size_t)255;
        return r;
    };
    float* hW = (float*)alloc(sizeof(float) * (size_t)NNODES * HID);
    float* h = (float*)alloc(sizeof(float) * (size_t)NNODES * HID);
    float* dis = (float*)alloc(sizeof(float) * NNODES);
    int* deg = (int*)alloc(sizeof(int) * NNODES);
    int* row_ptr = (int*)alloc(sizeof(int) * (NNODES + 1));
    int* cursor = (int*)alloc(sizeof(int) * NNODES);
    int* csr_src = (int*)alloc(sizeof(int) * NEDGES);
    float* csr_norm = (float*)alloc(sizeof(float) * NEDGES);
    int* bsum = (int*)alloc(sizeof(int) * 128);
    int* gstart = (int*)alloc(sizeof(int) * (NGRAPHS + 1));
    float* z = (float*)alloc(sizeof(float) * NGRAPHS * (HID + 2));
    (void)ws_size; (void)in_sizes; (void)n_in; (void)out_size;

    hipMemsetAsync(deg, 0, sizeof(int) * NNODES, stream);
    deg_kernel<<<(NEDGES + 255) / 256, 256, 0, stream>>>(dst, deg);
    dis_kernel<<<(NNODES + 255) / 256, 256, 0, stream>>>(deg, dis);
    scan1<<<SCAN_NB, SCAN_B, 0, stream>>>(deg, row_ptr, bsum);
    scan2<<<1, 128, 0, stream>>>(bsum);
    scan3<<<SCAN_NB, SCAN_B, 0, stream>>>(row_ptr, bsum);
    hipMemcpyAsync(cursor, row_ptr, sizeof(int) * NNODES, hipMemcpyDeviceToDevice, stream);
    fill_csr<<<(NEDGES + 255) / 256, 256, 0, stream>>>(src, dst, dis, cursor, csr_src, csr_norm);

    dim3 ggrid(HID / 64, (NNODES + 63) / 64);
    // layer 0
    gemm_f32<<<ggrid, 256, 0, stream>>>(x, W0, hW, NNODES, HID, INCH);
    aggregate_k<<<(NNODES + 3) / 4, 256, 0, stream>>>((const float4*)hW, row_ptr, csr_src, csr_norm, dis, b0,
                                                      (float4*)h);
    // layer 1
    gemm_f32<<<ggrid, 256, 0, stream>>>(h, W1, hW, NNODES, HID, HID);
    aggregate_k<<<(NNODES + 3) / 4, 256, 0, stream>>>((const float4*)hW, row_ptr, csr_src, csr_norm, dis, b1,
                                                      (float4*)h);
    // layer 2
    gemm_f32<<<ggrid, 256, 0, stream>>>(h, W2, hW, NNODES, HID, HID);
    aggregate_k<<<(NNODES + 3) / 4, 256, 0, stream>>>((const float4*)hW, row_ptr, csr_src, csr_norm, dis, b2,
                                                      (float4*)h);

    graph_bounds<<<(NNODES + 255) / 256, 256, 0, stream>>>(batch, gstart);
    pool_k<<<NGRAPHS, HID, 0, stream>>>(h, gstart, hlr, stdv, z);
    fc_k<<<NGRAPHS, HID, 0, stream>>>(z, fcW0, fcb0, fcW1, fcb1, out);
}

// Round 2
// 674.765 us; speedup vs baseline: 1.3755x; 1.3755x over previous
//
#include <hip/hip_runtime.h>

#define NNODES 50000
#define NEDGES 800000
#define NGRAPHS 64
#define INCH 128
#define HID 256
#define ZSTR (HID + 2)
#define SCAN_B 512
#define SCAN_NB ((NNODES + SCAN_B - 1) / SCAN_B)   // 98
#define NSLICE 16

// ---------------- degree / dis ----------------
__global__ __launch_bounds__(256) void deg_kernel(const int* __restrict__ dst, int* __restrict__ deg) {
    int e = blockIdx.x * 256 + threadIdx.x;
    if (e < NEDGES) atomicAdd(&deg[dst[e]], 1);
}

__global__ __launch_bounds__(256) void dis_kernel(const int* __restrict__ deg, float* __restrict__ dis) {
    int i = blockIdx.x * 256 + threadIdx.x;
    if (i < NNODES) dis[i] = rsqrtf((float)deg[i] + 1.0f);
}

// ---------------- scan (row_ptr from deg) ----------------
__global__ __launch_bounds__(SCAN_B) void scan1(const int* __restrict__ deg, int* __restrict__ row_ptr,
                                                int* __restrict__ bsum) {
    __shared__ int s[SCAN_B];
    int t = threadIdx.x;
    int i = blockIdx.x * SCAN_B + t;
    int v = (i < NNODES) ? deg[i] : 0;
    s[t] = v;
    __syncthreads();
    for (int off = 1; off < SCAN_B; off <<= 1) {
        int x = (t >= off) ? s[t - off] : 0;
        __syncthreads();
        if (t >= off) s[t] += x;
        __syncthreads();
    }
    if (i < NNODES) row_ptr[i + 1] = s[t];
    if (t == SCAN_B - 1) bsum[blockIdx.x] = s[t];
}

__global__ __launch_bounds__(128) void scan2(int* __restrict__ bsum) {
    __shared__ int s[128];
    int t = threadIdx.x;
    int v = (t < SCAN_NB) ? bsum[t] : 0;
    s[t] = v;
    __syncthreads();
    for (int off = 1; off < 128; off <<= 1) {
        int x = (t >= off) ? s[t - off] : 0;
        __syncthreads();
        if (t >= off) s[t] += x;
        __syncthreads();
    }
    if (t < SCAN_NB) bsum[t] = s[t];
}

__global__ __launch_bounds__(SCAN_B) void scan3(int* __restrict__ row_ptr, const int* __restrict__ bsum) {
    int b = blockIdx.x, t = threadIdx.x;
    int i = b * SCAN_B + t;
    if (i == 0) row_ptr[0] = 0;
    if (i < NNODES && b > 0) row_ptr[i + 1] += bsum[b - 1];
}

// ---------------- CSR fill ----------------
__global__ __launch_bounds__(256) void fill_csr(const int* __restrict__ src, const int* __restrict__ dst,
                                                const float* __restrict__ dis, int* __restrict__ cursor,
                                                int* __restrict__ csr_src, float* __restrict__ csr_norm) {
    int e = blockIdx.x * 256 + threadIdx.x;
    if (e >= NEDGES) return;
    int s = src[e], d = dst[e];
    int pos = atomicAdd(&cursor[d], 1);
    csr_src[pos] = s;
    csr_norm[pos] = dis[s] * dis[d];
}

// ---------------- aggregate (pre-GEMM): agg_i = sum_{j->i} norm*h[j] + dis_i^2*h[i] ----------------
template <int CH4>   // CH4 = channels/4 : 32 (128ch) or 64 (256ch)
__global__ __launch_bounds__(256) void aggregate_t(const float4* __restrict__ h, const int* __restrict__ row_ptr,
                                                   const int* __restrict__ csr_src,
                                                   const float* __restrict__ csr_norm,
                                                   const float* __restrict__ dis, float4* __restrict__ out) {
    constexpr int GPB = 256 / CH4;   // nodes per block
    int node = blockIdx.x * GPB + (int)(threadIdx.x / CH4);
    if (node >= NNODES) return;
    int lane = threadIdx.x & (CH4 - 1);
    float d = dis[node];
    float sw = d * d;
    float4 acc = h[(size_t)node * CH4 + lane];
    acc.x *= sw; acc.y *= sw; acc.z *= sw; acc.w *= sw;
    int e = row_ptr[node], e1 = row_ptr[node + 1];
    for (; e + 1 < e1; e += 2) {
        int s0 = csr_src[e], s1 = csr_src[e + 1];
        float w0 = csr_norm[e], w1 = csr_norm[e + 1];
        float4 v0 = h[(size_t)s0 * CH4 + lane];
        float4 v1 = h[(size_t)s1 * CH4 + lane];
        acc.x += w0 * v0.x + w1 * v1.x;
        acc.y += w0 * v0.y + w1 * v1.y;
        acc.z += w0 * v0.z + w1 * v1.z;
        acc.w += w0 * v0.w + w1 * v1.w;
    }
    if (e < e1) {
        int s0 = csr_src[e];
        float w0 = csr_norm[e];
        float4 v0 = h[(size_t)s0 * CH4 + lane];
        acc.x += w0 * v0.x; acc.y += w0 * v0.y; acc.z += w0 * v0.z; acc.w += w0 * v0.w;
    }
    out[(size_t)node * CH4 + lane] = acc;
}

// ---------------- fp32 GEMM 128x128 tile, 8x8/thread, fused bias+relu ----------------
// C[M x 256] = relu(A[M x K] @ B[K x 256] + bias)
__global__ __launch_bounds__(256) void gemm_bias_relu(const float* __restrict__ A, const float* __restrict__ B,
                                                      const float* __restrict__ bias, float* __restrict__ C,
                                                      int M, int K) {
    __shared__ float As[16][128];
    __shared__ float Bs[16][128];
    const int t = threadIdx.x;
    const int tx = t & 15, ty = t >> 4;
    const int row0 = blockIdx.y * 128, col0 = blockIdx.x * 128;
    const int ar = t >> 1, ac = (t & 1) << 3;          // A: 128 rows x 16 k
    const int br = t >> 4, bc = (t & 15) << 3;         // B: 16 k x 128 cols
    float acc[8][8] = {{0.f}};
    for (int k0 = 0; k0 < K; k0 += 16) {
        int grow = row0 + ar;
        if (grow > M - 1) grow = M - 1;
        float4 a0 = *(const float4*)&A[(size_t)grow * K + k0 + ac];
        float4 a1 = *(const float4*)&A[(size_t)grow * K + k0 + ac + 4];
        float4 b0 = *(const float4*)&B[(size_t)(k0 + br) * HID + col0 + bc];
        float4 b1 = *(const float4*)&B[(size_t)(k0 + br) * HID + col0 + bc + 4];
        __syncthreads();
        As[ac + 0][ar] = a0.x; As[ac + 1][ar] = a0.y; As[ac + 2][ar] = a0.z; As[ac + 3][ar] = a0.w;
        As[ac + 4][ar] = a1.x; As[ac + 5][ar] = a1.y; As[ac + 6][ar] = a1.z; As[ac + 7][ar] = a1.w;
        *(float4*)&Bs[br][bc] = b0;
        *(float4*)&Bs[br][bc + 4] = b1;
        __syncthreads();
#pragma unroll
        for (int kk = 0; kk < 16; ++kk) {
            float a[8], b[8];
            *(float4*)&a[0] = *(const float4*)&As[kk][ty << 2];
            *(float4*)&a[4] = *(const float4*)&As[kk][(ty << 2) + 64];
            *(float4*)&b[0] = *(const float4*)&Bs[kk][tx << 2];
            *(float4*)&b[4] = *(const float4*)&Bs[kk][(tx << 2) + 64];
#pragma unroll
            for (int i = 0; i < 8; ++i)
#pragma unroll
                for (int j = 0; j < 8; ++j) acc[i][j] += a[i] * b[j];
        }
    }
    float bv[8];
#pragma unroll
    for (int j = 0; j < 8; ++j) {
        int c = col0 + (tx << 2) + (j < 4 ? j : 60 + j);
        bv[j] = bias[c];
    }
#pragma unroll
    for (int i = 0; i < 8; ++i) {
        int r = row0 + (ty << 2) + (i < 4 ? i : 60 + i);
        if (r >= M) continue;
        float4 o0 = make_float4(fmaxf(acc[i][0] + bv[0], 0.f), fmaxf(acc[i][1] + bv[1], 0.f),
                                fmaxf(acc[i][2] + bv[2], 0.f), fmaxf(acc[i][3] + bv[3], 0.f));
        float4 o1 = make_float4(fmaxf(acc[i][4] + bv[4], 0.f), fmaxf(acc[i][5] + bv[5], 0.f),
                                fmaxf(acc[i][6] + bv[6], 0.f), fmaxf(acc[i][7] + bv[7], 0.f));
        *(float4*)&C[(size_t)r * HID + col0 + (tx << 2)] = o0;
        *(float4*)&C[(size_t)r * HID + col0 + (tx << 2) + 64] = o1;
    }
}

// ---------------- graph boundaries from sorted batch ----------------
__global__ __launch_bounds__(256) void graph_bounds(const int* __restrict__ batch, int* __restrict__ gstart) {
    int i = blockIdx.x * 256 + threadIdx.x;
    if (i >= NNODES) return;
    int b = batch[i];
    if (i == 0) {
        for (int g = 0; g <= b; ++g) gstart[g] = 0;
    } else {
        int pb = batch[i - 1];
        for (int g = pb + 1; g <= b; ++g) gstart[g] = i;
    }
    if (i == NNODES - 1) {
        for (int g = b + 1; g <= NGRAPHS; ++g) gstart[g] = NNODES;
    }
}

// ---------------- mean pool: sliced, atomic partial sums ----------------
__global__ __launch_bounds__(HID) void pool_partial(const float* __restrict__ h, const int* __restrict__ gstart,
                                                    float* __restrict__ z) {
    int g = blockIdx.x;
    int s = blockIdx.y;
    int t = threadIdx.x;
    int n0 = gstart[g], n1 = gstart[g + 1];
    int cnt = n1 - n0;
    if (cnt <= 0) return;
    int len = (cnt + NSLICE - 1) / NSLICE;
    int a = n0 + s * len;
    int b = a + len < n1 ? a + len : n1;
    if (a >= b) return;
    float acc = 0.f;
    for (int n = a; n < b; ++n) acc += h[(size_t)n * HID + t];
    atomicAdd(&z[g * ZSTR + t], acc);
}

__global__ __launch_bounds__(HID) void pool_finalize(const int* __restrict__ gstart, const float* __restrict__ hlr,
                                                     const float* __restrict__ stdv, float* __restrict__ z) {
    int g = blockIdx.x;
    int t = threadIdx.x;
    int cnt = gstart[g + 1] - gstart[g];
    float inv = 1.f / (float)(cnt > 0 ? cnt : 1);
    z[g * ZSTR + t] *= inv;
    if (t == 0) {
        z[g * ZSTR + HID] = hlr[g];
        z[g * ZSTR + HID + 1] = stdv[g];
    }
}

// ---------------- FC head: relu(z @ fcW0 + fcb0) @ fcW1 + fcb1 ----------------
__global__ __launch_bounds__(HID) void fc_k(const float* __restrict__ z, const float* __restrict__ fcW0,
                                            const float* __restrict__ fcb0, const float* __restrict__ fcW1,
                                            const float* __restrict__ fcb1, float* __restrict__ out) {
    __shared__ float zs[ZSTR];
    __shared__ float z2[HID];
    int g = blockIdx.x;
    int t = threadIdx.x;
    zs[t] = z[g * ZSTR + t];
    if (t < 2) zs[HID + t] = z[g * ZSTR + HID + t];
    __syncthreads();
    float acc = fcb0[t];
    for (int k = 0; k < ZSTR; ++k) acc += zs[k] * fcW0[k * HID + t];
    z2[t] = fmaxf(acc, 0.f);
    __syncthreads();
    if (t < INCH) {
        float acc2 = fcb1[t];
        for (int k = 0; k < HID; ++k) acc2 += z2[k] * fcW1[k * INCH + t];
        out[g * INCH + t] = acc2;
    }
}

extern "C" void kernel_launch(void* const* d_in, const int* in_sizes, int n_in,
                              void* d_out, int out_size, void* d_ws, size_t ws_size,
                              hipStream_t stream) {
    const float* x = (const float*)d_in[0];
    const int* ei = (const int*)d_in[1];
    const int* src = ei;
    const int* dst = ei + NEDGES;
    const int* batch = (const int*)d_in[2];
    const float* hlr = (const float*)d_in[3];
    const float* stdv = (const float*)d_in[4];
    const float* W0 = (const float*)d_in[5];
    const float* b0 = (const float*)d_in[6];
    const float* W1 = (const float*)d_in[7];
    const float* b1 = (const float*)d_in[8];
    const float* W2 = (const float*)d_in[9];
    const float* b2 = (const float*)d_in[10];
    const float* fcW0 = (const float*)d_in[11];
    const float* fcb0 = (const float*)d_in[12];
    const float* fcW1 = (const float*)d_in[13];
    const float* fcb1 = (const float*)d_in[14];
    float* out = (float*)d_out;

    char* p = (char*)d_ws;
    auto alloc = [&](size_t bytes) -> char* {
        char* r = p;
        p += (bytes + 255) & ~(size_t)255;
        return r;
    };
    float* agg = (float*)alloc(sizeof(float) * (size_t)NNODES * HID);   // aggregation output
    float* h = (float*)alloc(sizeof(float) * (size_t)NNODES * HID);     // layer activations
    float* dis = (float*)alloc(sizeof(float) * NNODES);
    int* deg = (int*)alloc(sizeof(int) * NNODES);
    int* row_ptr = (int*)alloc(sizeof(int) * (NNODES + 1));
    int* cursor = (int*)alloc(sizeof(int) * NNODES);
    int* csr_src = (int*)alloc(sizeof(int) * NEDGES);
    float* csr_norm = (float*)alloc(sizeof(float) * NEDGES);
    int* bsum = (int*)alloc(sizeof(int) * 128);
    int* gstart = (int*)alloc(sizeof(int) * (NGRAPHS + 1));
    float* z = (float*)alloc(sizeof(float) * NGRAPHS * ZSTR);
    (void)ws_size; (void)in_sizes; (void)n_in; (void)out_size;

    hipMemsetAsync(deg, 0, sizeof(int) * NNODES, stream);
    deg_kernel<<<(NEDGES + 255) / 256, 256, 0, stream>>>(dst, deg);
    dis_kernel<<<(NNODES + 255) / 256, 256, 0, stream>>>(deg, dis);
    scan1<<<SCAN_NB, SCAN_B, 0, stream>>>(deg, row_ptr, bsum);
    scan2<<<1, 128, 0, stream>>>(bsum);
    scan3<<<SCAN_NB, SCAN_B, 0, stream>>>(row_ptr, bsum);
    hipMemcpyAsync(cursor, row_ptr, sizeof(int) * NNODES, hipMemcpyDeviceToDevice, stream);
    fill_csr<<<(NEDGES + 255) / 256, 256, 0, stream>>>(src, dst, dis, cursor, csr_src, csr_norm);

    dim3 ggrid(HID / 128, (NNODES + 127) / 128);
    // layer 0: agg over x (128 ch), then GEMM K=128 with bias+relu
    aggregate_t<32><<<(NNODES * 32 + 255) / 256, 256, 0, stream>>>((const float4*)x, row_ptr, csr_src, csr_norm,
                                                                   dis, (float4*)agg);
    gemm_bias_relu<<<ggrid, 256, 0, stream>>>(agg, W0, b0, h, NNODES, INCH);
    // layer 1
    aggregate_t<64><<<(NNODES * 64 + 255) / 256, 256, 0, stream>>>((const float4*)h, row_ptr, csr_src, csr_norm,
                                                                   dis, (float4*)agg);
    gemm_bias_relu<<<ggrid, 256, 0, stream>>>(agg, W1, b1, h, NNODES, HID);
    // layer 2
    aggregate_t<64><<<(NNODES * 64 + 255) / 256, 256, 0, stream>>>((const float4*)h, row_ptr, csr_src, csr_norm,
                                                                   dis, (float4*)agg);
    gemm_bias_relu<<<ggrid, 256, 0, stream>>>(agg, W2, b2, h, NNODES, HID);

    graph_bounds<<<(NNODES + 255) / 256, 256, 0, stream>>>(batch, gstart);
    hipMemsetAsync(z, 0, sizeof(float) * NGRAPHS * ZSTR, stream);
    dim3 pgrid(NGRAPHS, NSLICE);
    pool_partial<<<pgrid, HID, 0, stream>>>(h, gstart, z);
    pool_finalize<<<NGRAPHS, HID, 0, stream>>>(gstart, hlr, stdv, z);
    fc_k<<<NGRAPHS, HID, 0, stream>>>(z, fcW0, fcb0, fcW1, fcb1, out);
}

// Round 3
// 465.469 us; speedup vs baseline: 1.9940x; 1.4496x over previous
//
#include <hip/hip_runtime.h>

#define NNODES 50000
#define NEDGES 800000
#define NGRAPHS 64
#define INCH 128
#define HID 256
#define ZSTR (HID + 2)
#define SCAN_B 512
#define SCAN_NB ((NNODES + SCAN_B - 1) / SCAN_B)   // 98
#define NSLICE 16

typedef __attribute__((ext_vector_type(8))) short short8v;
typedef __attribute__((ext_vector_type(4))) float f32x4;

__device__ inline ushort f2b(float f) {
    union { float f; unsigned u; } v; v.f = f;
    unsigned r = (v.u + 0x7FFFu + ((v.u >> 16) & 1u)) >> 16;
    return (ushort)r;
}
__device__ inline float b2f(ushort b) {
    union { unsigned u; float f; } v; v.u = ((unsigned)b) << 16;
    return v.f;
}

// ---------------- degree / dis ----------------
__global__ __launch_bounds__(256) void deg_kernel(const int* __restrict__ dst, int* __restrict__ deg) {
    int e = blockIdx.x * 256 + threadIdx.x;
    if (e < NEDGES) atomicAdd(&deg[dst[e]], 1);
}

__global__ __launch_bounds__(256) void dis_kernel(const int* __restrict__ deg, float* __restrict__ dis) {
    int i = blockIdx.x * 256 + threadIdx.x;
    if (i < NNODES) dis[i] = rsqrtf((float)deg[i] + 1.0f);
}

// ---------------- scan (row_ptr from deg) ----------------
__global__ __launch_bounds__(SCAN_B) void scan1(const int* __restrict__ deg, int* __restrict__ row_ptr,
                                                int* __restrict__ bsum) {
    __shared__ int s[SCAN_B];
    int t = threadIdx.x;
    int i = blockIdx.x * SCAN_B + t;
    int v = (i < NNODES) ? deg[i] : 0;
    s[t] = v;
    __syncthreads();
    for (int off = 1; off < SCAN_B; off <<= 1) {
        int x = (t >= off) ? s[t - off] : 0;
        __syncthreads();
        if (t >= off) s[t] += x;
        __syncthreads();
    }
    if (i < NNODES) row_ptr[i + 1] = s[t];
    if (t == SCAN_B - 1) bsum[blockIdx.x] = s[t];
}

__global__ __launch_bounds__(128) void scan2(int* __restrict__ bsum) {
    __shared__ int s[128];
    int t = threadIdx.x;
    int v = (t < SCAN_NB) ? bsum[t] : 0;
    s[t] = v;
    __syncthreads();
    for (int off = 1; off < 128; off <<= 1) {
        int x = (t >= off) ? s[t - off] : 0;
        __syncthreads();
        if (t >= off) s[t] += x;
        __syncthreads();
    }
    if (t < SCAN_NB) bsum[t] = s[t];
}

__global__ __launch_bounds__(SCAN_B) void scan3(int* __restrict__ row_ptr, const int* __restrict__ bsum) {
    int b = blockIdx.x, t = threadIdx.x;
    int i = b * SCAN_B + t;
    if (i == 0) row_ptr[0] = 0;
    if (i < NNODES && b > 0) row_ptr[i + 1] += bsum[b - 1];
}

// ---------------- CSR fill ----------------
__global__ __launch_bounds__(256) void fill_csr(const int* __restrict__ src, const int* __restrict__ dst,
                                                const float* __restrict__ dis, int* __restrict__ cursor,
                                                int* __restrict__ csr_src, float* __restrict__ csr_norm) {
    int e = blockIdx.x * 256 + threadIdx.x;
    if (e >= NEDGES) return;
    int s = src[e], d = dst[e];
    int pos = atomicAdd(&cursor[d], 1);
    csr_src[pos] = s;
    csr_norm[pos] = dis[s] * dis[d];
}

// ---------------- conversions ----------------
__global__ __launch_bounds__(256) void xcvt(const float4* __restrict__ x, ushort4* __restrict__ xb, int n4) {
    int i = blockIdx.x * 256 + threadIdx.x;
    if (i >= n4) return;
    float4 v = x[i];
    ushort4 o;
    o.x = f2b(v.x); o.y = f2b(v.y); o.z = f2b(v.z); o.w = f2b(v.w);
    xb[i] = o;
}

// W[K x N] fp32 -> Wt[N x K] bf16
__global__ __launch_bounds__(256) void wcvt(const float* __restrict__ W, ushort* __restrict__ Wt, int K, int N) {
    int i = blockIdx.x * 256 + threadIdx.x;
    if (i >= K * N) return;
    int k = i / N, n = i - k * N;
    Wt[n * K + k] = f2b(W[i]);
}

// ---------------- aggregate (bf16): agg_i = sum_{j->i} norm*h[j] + dis_i^2*h[i] ----------------
template <int CHL>   // lanes per node = channels/4 : 32 (128ch) or 64 (256ch)
__global__ __launch_bounds__(256) void aggregate_bf(const ushort4* __restrict__ h, const int* __restrict__ row_ptr,
                                                    const int* __restrict__ csr_src,
                                                    const float* __restrict__ csr_norm,
                                                    const float* __restrict__ dis, ushort4* __restrict__ out) {
    constexpr int NPB = 256 / CHL;
    int node = blockIdx.x * NPB + (int)(threadIdx.x / CHL);
    if (node >= NNODES) return;
    int lane = threadIdx.x & (CHL - 1);
    float d = dis[node];
    float sw = d * d;
    ushort4 hv = h[(size_t)node * CHL + lane];
    float ax = sw * b2f(hv.x), ay = sw * b2f(hv.y), az = sw * b2f(hv.z), aw = sw * b2f(hv.w);
    int e = row_ptr[node], e1 = row_ptr[node + 1];
    for (; e + 1 < e1; e += 2) {
        int s0 = csr_src[e], s1 = csr_src[e + 1];
        float w0 = csr_norm[e], w1 = csr_norm[e + 1];
        ushort4 v0 = h[(size_t)s0 * CHL + lane];
        ushort4 v1 = h[(size_t)s1 * CHL + lane];
        ax += w0 * b2f(v0.x) + w1 * b2f(v1.x);
        ay += w0 * b2f(v0.y) + w1 * b2f(v1.y);
        az += w0 * b2f(v0.z) + w1 * b2f(v1.z);
        aw += w0 * b2f(v0.w) + w1 * b2f(v1.w);
    }
    if (e < e1) {
        int s0 = csr_src[e];
        float w0 = csr_norm[e];
        ushort4 v0 = h[(size_t)s0 * CHL + lane];
        ax += w0 * b2f(v0.x); ay += w0 * b2f(v0.y); az += w0 * b2f(v0.z); aw += w0 * b2f(v0.w);
    }
    ushort4 o;
    o.x = f2b(ax); o.y = f2b(ay); o.z = f2b(az); o.w = f2b(aw);
    out[(size_t)node * CHL + lane] = o;
}

// ---------------- MFMA GEMM: C[M x 256] = relu(A[M x K] @ W + bias) ----------------
// A: bf16 row-major [M x K]; Bt: bf16 [256 x K] (= W transposed); C: bf16 [M x 256]
__global__ __launch_bounds__(256) void gemm_mfma(const ushort* __restrict__ A, const ushort* __restrict__ Bt,
                                                 const float* __restrict__ bias, ushort* __restrict__ C,
                                                 int M, int K) {
    const int tid = threadIdx.x;
    const int w = tid >> 6, l = tid & 63;
    const int wr = w >> 1, wc = w & 1;
    const int r16 = l & 15, kg = l >> 4;
    const int R = blockIdx.y * 128 + wr * 64;
    const int Cb = blockIdx.x * 128 + wc * 64;
    f32x4 acc[4][4] = {};
    for (int k0 = 0; k0 < K; k0 += 32) {
        int k = k0 + kg * 8;
        short8v a[4], b[4];
#pragma unroll
        for (int m = 0; m < 4; ++m) {
            int row = R + m * 16 + r16;
            if (row > M - 1) row = M - 1;
            a[m] = *(const short8v*)&A[(size_t)row * K + k];
        }
#pragma unroll
        for (int n = 0; n < 4; ++n) {
            int col = Cb + n * 16 + r16;
            b[n] = *(const short8v*)&Bt[(size_t)col * K + k];
        }
#pragma unroll
        for (int m = 0; m < 4; ++m)
#pragma unroll
            for (int n = 0; n < 4; ++n)
                acc[m][n] = __builtin_amdgcn_mfma_f32_16x16x32_bf16(a[m], b[n], acc[m][n], 0, 0, 0);
    }
#pragma unroll
    for (int n = 0; n < 4; ++n) {
        int col = Cb + n * 16 + r16;
        float bv = bias[col];
#pragma unroll
        for (int m = 0; m < 4; ++m) {
#pragma unroll
            for (int j = 0; j < 4; ++j) {
                int row = R + m * 16 + kg * 4 + j;
                if (row < M) {
                    float v = fmaxf(acc[m][n][j] + bv, 0.f);
                    C[(size_t)row * HID + col] = f2b(v);
                }
            }
        }
    }
}

// ---------------- graph boundaries from sorted batch ----------------
__global__ __launch_bounds__(256) void graph_bounds(const int* __restrict__ batch, int* __restrict__ gstart) {
    int i = blockIdx.x * 256 + threadIdx.x;
    if (i >= NNODES) return;
    int b = batch[i];
    if (i == 0) {
        for (int g = 0; g <= b; ++g) gstart[g] = 0;
    } else {
        int pb = batch[i - 1];
        for (int g = pb + 1; g <= b; ++g) gstart[g] = i;
    }
    if (i == NNODES - 1) {
        for (int g = b + 1; g <= NGRAPHS; ++g) gstart[g] = NNODES;
    }
}

// ---------------- mean pool: sliced, atomic partial sums (h is bf16) ----------------
__global__ __launch_bounds__(HID) void pool_partial(const ushort* __restrict__ h, const int* __restrict__ gstart,
                                                    float* __restrict__ z) {
    int g = blockIdx.x;
    int s = blockIdx.y;
    int t = threadIdx.x;
    int n0 = gstart[g], n1 = gstart[g + 1];
    int cnt = n1 - n0;
    if (cnt <= 0) return;
    int len = (cnt + NSLICE - 1) / NSLICE;
    int a = n0 + s * len;
    int b = a + len < n1 ? a + len : n1;
    if (a >= b) return;
    float acc = 0.f;
    for (int n = a; n < b; ++n) acc += b2f(h[(size_t)n * HID + t]);
    atomicAdd(&z[g * ZSTR + t], acc);
}

__global__ __launch_bounds__(HID) void pool_finalize(const int* __restrict__ gstart, const float* __restrict__ hlr,
                                                     const float* __restrict__ stdv, float* __restrict__ z) {
    int g = blockIdx.x;
    int t = threadIdx.x;
    int cnt = gstart[g + 1] - gstart[g];
    float inv = 1.f / (float)(cnt > 0 ? cnt : 1);
    z[g * ZSTR + t] *= inv;
    if (t == 0) {
        z[g * ZSTR + HID] = hlr[g];
        z[g * ZSTR + HID + 1] = stdv[g];
    }
}

// ---------------- FC head: relu(z @ fcW0 + fcb0) @ fcW1 + fcb1 ----------------
__global__ __launch_bounds__(HID) void fc_k(const float* __restrict__ z, const float* __restrict__ fcW0,
                                            const float* __restrict__ fcb0, const float* __restrict__ fcW1,
                                            const float* __restrict__ fcb1, float* __restrict__ out) {
    __shared__ float zs[ZSTR];
    __shared__ float z2[HID];
    int g = blockIdx.x;
    int t = threadIdx.x;
    zs[t] = z[g * ZSTR + t];
    if (t < 2) zs[HID + t] = z[g * ZSTR + HID + t];
    __syncthreads();
    float acc = fcb0[t];
    for (int k = 0; k < ZSTR; ++k) acc += zs[k] * fcW0[k * HID + t];
    z2[t] = fmaxf(acc, 0.f);
    __syncthreads();
    if (t < INCH) {
        float acc2 = fcb1[t];
        for (int k = 0; k < HID; ++k) acc2 += z2[k] * fcW1[k * INCH + t];
        out[g * INCH + t] = acc2;
    }
}

extern "C" void kernel_launch(void* const* d_in, const int* in_sizes, int n_in,
                              void* d_out, int out_size, void* d_ws, size_t ws_size,
                              hipStream_t stream) {
    const float* x = (const float*)d_in[0];
    const int* ei = (const int*)d_in[1];
    const int* src = ei;
    const int* dst = ei + NEDGES;
    const int* batch = (const int*)d_in[2];
    const float* hlr = (const float*)d_in[3];
    const float* stdv = (const float*)d_in[4];
    const float* W0 = (const float*)d_in[5];
    const float* b0 = (const float*)d_in[6];
    const float* W1 = (const float*)d_in[7];
    const float* b1 = (const float*)d_in[8];
    const float* W2 = (const float*)d_in[9];
    const float* b2 = (const float*)d_in[10];
    const float* fcW0 = (const float*)d_in[11];
    const float* fcb0 = (const float*)d_in[12];
    const float* fcW1 = (const float*)d_in[13];
    const float* fcb1 = (const float*)d_in[14];
    float* out = (float*)d_out;

    char* p = (char*)d_ws;
    auto alloc = [&](size_t bytes) -> char* {
        char* r = p;
        p += (bytes + 255) & ~(size_t)255;
        return r;
    };
    ushort* xb = (ushort*)alloc(sizeof(ushort) * (size_t)NNODES * INCH);
    ushort* agg = (ushort*)alloc(sizeof(ushort) * (size_t)NNODES * HID);
    ushort* h = (ushort*)alloc(sizeof(ushort) * (size_t)NNODES * HID);
    ushort* Wt0 = (ushort*)alloc(sizeof(ushort) * HID * INCH);
    ushort* Wt1 = (ushort*)alloc(sizeof(ushort) * HID * HID);
    ushort* Wt2 = (ushort*)alloc(sizeof(ushort) * HID * HID);
    float* dis = (float*)alloc(sizeof(float) * NNODES);
    int* deg = (int*)alloc(sizeof(int) * NNODES);
    int* row_ptr = (int*)alloc(sizeof(int) * (NNODES + 1));
    int* cursor = (int*)alloc(sizeof(int) * NNODES);
    int* csr_src = (int*)alloc(sizeof(int) * NEDGES);
    float* csr_norm = (float*)alloc(sizeof(float) * NEDGES);
    int* bsum = (int*)alloc(sizeof(int) * 128);
    int* gstart = (int*)alloc(sizeof(int) * (NGRAPHS + 1));
    float* z = (float*)alloc(sizeof(float) * NGRAPHS * ZSTR);
    (void)ws_size; (void)in_sizes; (void)n_in; (void)out_size;

    hipMemsetAsync(deg, 0, sizeof(int) * NNODES, stream);
    deg_kernel<<<(NEDGES + 255) / 256, 256, 0, stream>>>(dst, deg);
    dis_kernel<<<(NNODES + 255) / 256, 256, 0, stream>>>(deg, dis);
    scan1<<<SCAN_NB, SCAN_B, 0, stream>>>(deg, row_ptr, bsum);
    scan2<<<1, 128, 0, stream>>>(bsum);
    scan3<<<SCAN_NB, SCAN_B, 0, stream>>>(row_ptr, bsum);
    hipMemcpyAsync(cursor, row_ptr, sizeof(int) * NNODES, hipMemcpyDeviceToDevice, stream);
    fill_csr<<<(NEDGES + 255) / 256, 256, 0, stream>>>(src, dst, dis, cursor, csr_src, csr_norm);

    // conversions
    xcvt<<<(NNODES * INCH / 4 + 255) / 256, 256, 0, stream>>>((const float4*)x, (ushort4*)xb, NNODES * INCH / 4);
    wcvt<<<(INCH * HID + 255) / 256, 256, 0, stream>>>(W0, Wt0, INCH, HID);
    wcvt<<<(HID * HID + 255) / 256, 256, 0, stream>>>(W1, Wt1, HID, HID);
    wcvt<<<(HID * HID + 255) / 256, 256, 0, stream>>>(W2, Wt2, HID, HID);

    dim3 ggrid(HID / 128, (NNODES + 127) / 128);
    // layer 0: agg over x (128 ch), then MFMA GEMM K=128 with bias+relu
    aggregate_bf<32><<<(NNODES + 7) / 8, 256, 0, stream>>>((const ushort4*)xb, row_ptr, csr_src, csr_norm, dis,
                                                           (ushort4*)agg);
    gemm_mfma<<<ggrid, 256, 0, stream>>>(agg, Wt0, b0, h, NNODES, INCH);
    // layer 1
    aggregate_bf<64><<<(NNODES + 3) / 4, 256, 0, stream>>>((const ushort4*)h, row_ptr, csr_src, csr_norm, dis,
                                                           (ushort4*)agg);
    gemm_mfma<<<ggrid, 256, 0, stream>>>(agg, Wt1, b1, h, NNODES, HID);
    // layer 2
    aggregate_bf<64><<<(NNODES + 3) / 4, 256, 0, stream>>>((const ushort4*)h, row_ptr, csr_src, csr_norm, dis,
                                                           (ushort4*)agg);
    gemm_mfma<<<ggrid, 256, 0, stream>>>(agg, Wt2, b2, h, NNODES, HID);

    graph_bounds<<<(NNODES + 255) / 256, 256, 0, stream>>>(batch, gstart);
    hipMemsetAsync(z, 0, sizeof(float) * NGRAPHS * ZSTR, stream);
    dim3 pgrid(NGRAPHS, NSLICE);
    pool_partial<<<pgrid, HID, 0, stream>>>(h, gstart, z);
    pool_finalize<<<NGRAPHS, HID, 0, stream>>>(gstart, hlr, stdv, z);
    fc_k<<<NGRAPHS, HID, 0, stream>>>(z, fcW0, fcb0, fcW1, fcb1, out);
}

// Round 4
// 412.967 us; speedup vs baseline: 2.2475x; 1.1271x over previous
//
#include <hip/hip_runtime.h>

#define NNODES 50000
#define NEDGES 800000
#define NGRAPHS 64
#define INCH 128
#define HID 256
#define ZSTR (HID + 2)
#define SCAN_B 512
#define SCAN_NB ((NNODES + SCAN_B - 1) / SCAN_B)   // 98
#define NSLICE 16

typedef __attribute__((ext_vector_type(8))) short short8v;
typedef __attribute__((ext_vector_type(4))) float f32x4;

__device__ inline ushort f2b(float f) {
    union { float f; unsigned u; } v; v.f = f;
    unsigned r = (v.u + 0x7FFFu + ((v.u >> 16) & 1u)) >> 16;
    return (ushort)r;
}
__device__ inline float b2f(ushort b) {
    union { unsigned u; float f; } v; v.u = ((unsigned)b) << 16;
    return v.f;
}

// ---------------- degree / dis ----------------
__global__ __launch_bounds__(256) void deg_kernel(const int* __restrict__ dst, int* __restrict__ deg) {
    int e = blockIdx.x * 256 + threadIdx.x;
    if (e < NEDGES) atomicAdd(&deg[dst[e]], 1);
}

__global__ __launch_bounds__(256) void dis_kernel(const int* __restrict__ deg, float* __restrict__ dis) {
    int i = blockIdx.x * 256 + threadIdx.x;
    if (i < NNODES) dis[i] = rsqrtf((float)deg[i] + 1.0f);
}

// ---------------- scan (row_ptr from deg) ----------------
__global__ __launch_bounds__(SCAN_B) void scan1(const int* __restrict__ deg, int* __restrict__ row_ptr,
                                                int* __restrict__ bsum) {
    __shared__ int s[SCAN_B];
    int t = threadIdx.x;
    int i = blockIdx.x * SCAN_B + t;
    int v = (i < NNODES) ? deg[i] : 0;
    s[t] = v;
    __syncthreads();
    for (int off = 1; off < SCAN_B; off <<= 1) {
        int x = (t >= off) ? s[t - off] : 0;
        __syncthreads();
        if (t >= off) s[t] += x;
        __syncthreads();
    }
    if (i < NNODES) row_ptr[i + 1] = s[t];
    if (t == SCAN_B - 1) bsum[blockIdx.x] = s[t];
}

__global__ __launch_bounds__(128) void scan2(int* __restrict__ bsum) {
    __shared__ int s[128];
    int t = threadIdx.x;
    int v = (t < SCAN_NB) ? bsum[t] : 0;
    s[t] = v;
    __syncthreads();
    for (int off = 1; off < 128; off <<= 1) {
        int x = (t >= off) ? s[t - off] : 0;
        __syncthreads();
        if (t >= off) s[t] += x;
        __syncthreads();
    }
    if (t < SCAN_NB) bsum[t] = s[t];
}

__global__ __launch_bounds__(SCAN_B) void scan3(int* __restrict__ row_ptr, const int* __restrict__ bsum) {
    int b = blockIdx.x, t = threadIdx.x;
    int i = b * SCAN_B + t;
    if (i == 0) row_ptr[0] = 0;
    if (i < NNODES && b > 0) row_ptr[i + 1] += bsum[b - 1];
}

// ---------------- CSR fill (src only; norm is factorized away) ----------------
__global__ __launch_bounds__(256) void fill_csr(const int* __restrict__ src, const int* __restrict__ dst,
                                                int* __restrict__ cursor, int* __restrict__ csr_src) {
    int e = blockIdx.x * 256 + threadIdx.x;
    if (e >= NEDGES) return;
    int s = src[e], d = dst[e];
    int pos = atomicAdd(&cursor[d], 1);
    csr_src[pos] = s;
}

// ---------------- x' = dis * x -> bf16 ----------------
__global__ __launch_bounds__(256) void xcvt(const float4* __restrict__ x, const float* __restrict__ dis,
                                            ushort4* __restrict__ xb, int n4) {
    int i = blockIdx.x * 256 + threadIdx.x;
    if (i >= n4) return;
    float d = dis[i >> 5];   // 32 float4 per node (128 ch)
    float4 v = x[i];
    ushort4 o;
    o.x = f2b(d * v.x); o.y = f2b(d * v.y); o.z = f2b(d * v.z); o.w = f2b(d * v.w);
    xb[i] = o;
}

// W[K x N] fp32 -> Wt[N x K] bf16
__global__ __launch_bounds__(256) void wcvt(const float* __restrict__ W, ushort* __restrict__ Wt, int K, int N) {
    int i = blockIdx.x * 256 + threadIdx.x;
    if (i >= K * N) return;
    int k = i / N, n = i - k * N;
    Wt[n * K + k] = f2b(W[i]);
}

// ---------------- aggregate: S_i = f'_i + sum_{j->i} f'_j (pure gather-sum) ----------------
template <int CHL>   // lanes per node = channels/4 : 32 (128ch) or 64 (256ch)
__global__ __launch_bounds__(256) void aggregate_bf(const ushort4* __restrict__ h, const int* __restrict__ row_ptr,
                                                    const int* __restrict__ csr_src, ushort4* __restrict__ out) {
    constexpr int NPB = 256 / CHL;
    int node = blockIdx.x * NPB + (int)(threadIdx.x / CHL);
    if (node >= NNODES) return;
    int lane = threadIdx.x & (CHL - 1);
    ushort4 hv = h[(size_t)node * CHL + lane];
    float ax = b2f(hv.x), ay = b2f(hv.y), az = b2f(hv.z), aw = b2f(hv.w);
    int e = row_ptr[node], e1 = row_ptr[node + 1];
    for (; e + 3 < e1; e += 4) {
        int s0 = csr_src[e], s1 = csr_src[e + 1], s2 = csr_src[e + 2], s3 = csr_src[e + 3];
        ushort4 v0 = h[(size_t)s0 * CHL + lane];
        ushort4 v1 = h[(size_t)s1 * CHL + lane];
        ushort4 v2 = h[(size_t)s2 * CHL + lane];
        ushort4 v3 = h[(size_t)s3 * CHL + lane];
        ax += b2f(v0.x) + b2f(v1.x) + b2f(v2.x) + b2f(v3.x);
        ay += b2f(v0.y) + b2f(v1.y) + b2f(v2.y) + b2f(v3.y);
        az += b2f(v0.z) + b2f(v1.z) + b2f(v2.z) + b2f(v3.z);
        aw += b2f(v0.w) + b2f(v1.w) + b2f(v2.w) + b2f(v3.w);
    }
    for (; e < e1; ++e) {
        int s0 = csr_src[e];
        ushort4 v0 = h[(size_t)s0 * CHL + lane];
        ax += b2f(v0.x); ay += b2f(v0.y); az += b2f(v0.z); aw += b2f(v0.w);
    }
    ushort4 o;
    o.x = f2b(ax); o.y = f2b(ay); o.z = f2b(az); o.w = f2b(aw);
    out[(size_t)node * CHL + lane] = o;
}

// ---------------- MFMA GEMM: t = relu(dis_r * (S@W)_r + bias); store t (or dis_r*t) ----------------
// S: bf16 [M x K]; Bt: bf16 [256 x K]; C: bf16 [M x 256]. Block: 128 rows x 256 cols, 8 waves.
__global__ __launch_bounds__(512) void gemm_mfma(const ushort* __restrict__ A, const ushort* __restrict__ Bt,
                                                 const float* __restrict__ bias, const float* __restrict__ dis,
                                                 ushort* __restrict__ C, int M, int K, int scale_out) {
    const int tid = threadIdx.x;
    const int w = tid >> 6, l = tid & 63;
    const int wr = w >> 2, wc = w & 3;
    const int r16 = l & 15, kg = l >> 4;
    const int R = blockIdx.x * 128 + wr * 64;
    const int Cb = wc * 64;
    f32x4 acc[4][4] = {};
    for (int k0 = 0; k0 < K; k0 += 32) {
        int k = k0 + kg * 8;
        short8v a[4], b[4];
#pragma unroll
        for (int m = 0; m < 4; ++m) {
            int row = R + m * 16 + r16;
            if (row > M - 1) row = M - 1;
            a[m] = *(const short8v*)&A[(size_t)row * K + k];
        }
#pragma unroll
        for (int n = 0; n < 4; ++n) {
            int col = Cb + n * 16 + r16;
            b[n] = *(const short8v*)&Bt[(size_t)col * K + k];
        }
#pragma unroll
        for (int m = 0; m < 4; ++m)
#pragma unroll
            for (int n = 0; n < 4; ++n)
                acc[m][n] = __builtin_amdgcn_mfma_f32_16x16x32_bf16(a[m], b[n], acc[m][n], 0, 0, 0);
    }
    float bv[4];
#pragma unroll
    for (int n = 0; n < 4; ++n) bv[n] = bias[Cb + n * 16 + r16];
#pragma unroll
    for (int m = 0; m < 4; ++m) {
#pragma unroll
        for (int j = 0; j < 4; ++j) {
            int row = R + m * 16 + kg * 4 + j;
            if (row >= M) continue;
            float dr = dis[row];
            float os = scale_out ? dr : 1.0f;
#pragma unroll
            for (int n = 0; n < 4; ++n) {
                float v = fmaxf(dr * acc[m][n][j] + bv[n], 0.f) * os;
                C[(size_t)row * HID + Cb + n * 16 + r16] = f2b(v);
            }
        }
    }
}

// ---------------- graph boundaries from sorted batch ----------------
__global__ __launch_bounds__(256) void graph_bounds(const int* __restrict__ batch, int* __restrict__ gstart) {
    int i = blockIdx.x * 256 + threadIdx.x;
    if (i >= NNODES) return;
    int b = batch[i];
    if (i == 0) {
        for (int g = 0; g <= b; ++g) gstart[g] = 0;
    } else {
        int pb = batch[i - 1];
        for (int g = pb + 1; g <= b; ++g) gstart[g] = i;
    }
    if (i == NNODES - 1) {
        for (int g = b + 1; g <= NGRAPHS; ++g) gstart[g] = NNODES;
    }
}

// ---------------- mean pool: sliced, atomic partial sums (h is bf16) ----------------
__global__ __launch_bounds__(HID) void pool_partial(const ushort* __restrict__ h, const int* __restrict__ gstart,
                                                    float* __restrict__ z) {
    int g = blockIdx.x;
    int s = blockIdx.y;
    int t = threadIdx.x;
    int n0 = gstart[g], n1 = gstart[g + 1];
    int cnt = n1 - n0;
    if (cnt <= 0) return;
    int len = (cnt + NSLICE - 1) / NSLICE;
    int a = n0 + s * len;
    int b = a + len < n1 ? a + len : n1;
    if (a >= b) return;
    float acc = 0.f;
    for (int n = a; n < b; ++n) acc += b2f(h[(size_t)n * HID + t]);
    atomicAdd(&z[g * ZSTR + t], acc);
}

__global__ __launch_bounds__(HID) void pool_finalize(const int* __restrict__ gstart, const float* __restrict__ hlr,
                                                     const float* __restrict__ stdv, float* __restrict__ z) {
    int g = blockIdx.x;
    int t = threadIdx.x;
    int cnt = gstart[g + 1] - gstart[g];
    float inv = 1.f / (float)(cnt > 0 ? cnt : 1);
    z[g * ZSTR + t] *= inv;
    if (t == 0) {
        z[g * ZSTR + HID] = hlr[g];
        z[g * ZSTR + HID + 1] = stdv[g];
    }
}

// ---------------- FC head: relu(z @ fcW0 + fcb0) @ fcW1 + fcb1 ----------------
__global__ __launch_bounds__(HID) void fc_k(const float* __restrict__ z, const float* __restrict__ fcW0,
                                            const float* __restrict__ fcb0, const float* __restrict__ fcW1,
                                            const float* __restrict__ fcb1, float* __restrict__ out) {
    __shared__ float zs[ZSTR];
    __shared__ float z2[HID];
    int g = blockIdx.x;
    int t = threadIdx.x;
    zs[t] = z[g * ZSTR + t];
    if (t < 2) zs[HID + t] = z[g * ZSTR + HID + t];
    __syncthreads();
    float acc = fcb0[t];
    for (int k = 0; k < ZSTR; ++k) acc += zs[k] * fcW0[k * HID + t];
    z2[t] = fmaxf(acc, 0.f);
    __syncthreads();
    if (t < INCH) {
        float acc2 = fcb1[t];
        for (int k = 0; k < HID; ++k) acc2 += z2[k] * fcW1[k * INCH + t];
        out[g * INCH + t] = acc2;
    }
}

extern "C" void kernel_launch(void* const* d_in, const int* in_sizes, int n_in,
                              void* d_out, int out_size, void* d_ws, size_t ws_size,
                              hipStream_t stream) {
    const float* x = (const float*)d_in[0];
    const int* ei = (const int*)d_in[1];
    const int* src = ei;
    const int* dst = ei + NEDGES;
    const int* batch = (const int*)d_in[2];
    const float* hlr = (const float*)d_in[3];
    const float* stdv = (const float*)d_in[4];
    const float* W0 = (const float*)d_in[5];
    const float* b0 = (const float*)d_in[6];
    const float* W1 = (const float*)d_in[7];
    const float* b1 = (const float*)d_in[8];
    const float* W2 = (const float*)d_in[9];
    const float* b2 = (const float*)d_in[10];
    const float* fcW0 = (const float*)d_in[11];
    const float* fcb0 = (const float*)d_in[12];
    const float* fcW1 = (const float*)d_in[13];
    const float* fcb1 = (const float*)d_in[14];
    float* out = (float*)d_out;

    char* p = (char*)d_ws;
    auto alloc = [&](size_t bytes) -> char* {
        char* r = p;
        p += (bytes + 255) & ~(size_t)255;
        return r;
    };
    ushort* xb = (ushort*)alloc(sizeof(ushort) * (size_t)NNODES * INCH);
    ushort* agg = (ushort*)alloc(sizeof(ushort) * (size_t)NNODES * HID);
    ushort* h = (ushort*)alloc(sizeof(ushort) * (size_t)NNODES * HID);
    ushort* Wt0 = (ushort*)alloc(sizeof(ushort) * HID * INCH);
    ushort* Wt1 = (ushort*)alloc(sizeof(ushort) * HID * HID);
    ushort* Wt2 = (ushort*)alloc(sizeof(ushort) * HID * HID);
    float* dis = (float*)alloc(sizeof(float) * NNODES);
    int* deg = (int*)alloc(sizeof(int) * NNODES);
    int* row_ptr = (int*)alloc(sizeof(int) * (NNODES + 1));
    int* cursor = (int*)alloc(sizeof(int) * NNODES);
    int* csr_src = (int*)alloc(sizeof(int) * NEDGES);
    int* bsum = (int*)alloc(sizeof(int) * 128);
    int* gstart = (int*)alloc(sizeof(int) * (NGRAPHS + 1));
    float* z = (float*)alloc(sizeof(float) * NGRAPHS * ZSTR);
    (void)ws_size; (void)in_sizes; (void)n_in; (void)out_size;

    hipMemsetAsync(deg, 0, sizeof(int) * NNODES, stream);
    deg_kernel<<<(NEDGES + 255) / 256, 256, 0, stream>>>(dst, deg);
    dis_kernel<<<(NNODES + 255) / 256, 256, 0, stream>>>(deg, dis);
    scan1<<<SCAN_NB, SCAN_B, 0, stream>>>(deg, row_ptr, bsum);
    scan2<<<1, 128, 0, stream>>>(bsum);
    scan3<<<SCAN_NB, SCAN_B, 0, stream>>>(row_ptr, bsum);
    hipMemcpyAsync(cursor, row_ptr, sizeof(int) * NNODES, hipMemcpyDeviceToDevice, stream);
    fill_csr<<<(NEDGES + 255) / 256, 256, 0, stream>>>(src, dst, cursor, csr_src);

    // conversions (x' = dis * x)
    xcvt<<<(NNODES * INCH / 4 + 255) / 256, 256, 0, stream>>>((const float4*)x, dis, (ushort4*)xb,
                                                              NNODES * INCH / 4);
    wcvt<<<(INCH * HID + 255) / 256, 256, 0, stream>>>(W0, Wt0, INCH, HID);
    wcvt<<<(HID * HID + 255) / 256, 256, 0, stream>>>(W1, Wt1, HID, HID);
    wcvt<<<(HID * HID + 255) / 256, 256, 0, stream>>>(W2, Wt2, HID, HID);

    const int gblocks = (NNODES + 127) / 128;
    // layer 0: S = gather-sum(x'), h' = dis*relu(dis*(S@W0)+b0)
    aggregate_bf<32><<<(NNODES + 7) / 8, 256, 0, stream>>>((const ushort4*)xb, row_ptr, csr_src, (ushort4*)agg);
    gemm_mfma<<<gblocks, 512, 0, stream>>>(agg, Wt0, b0, dis, h, NNODES, INCH, 1);
    // layer 1
    aggregate_bf<64><<<(NNODES + 3) / 4, 256, 0, stream>>>((const ushort4*)h, row_ptr, csr_src, (ushort4*)agg);
    gemm_mfma<<<gblocks, 512, 0, stream>>>(agg, Wt1, b1, dis, h, NNODES, HID, 1);
    // layer 2 (unscaled output for pooling)
    aggregate_bf<64><<<(NNODES + 3) / 4, 256, 0, stream>>>((const ushort4*)h, row_ptr, csr_src, (ushort4*)agg);
    gemm_mfma<<<gblocks, 512, 0, stream>>>(agg, Wt2, b2, dis, h, NNODES, HID, 0);

    graph_bounds<<<(NNODES + 255) / 256, 256, 0, stream>>>(batch, gstart);
    hipMemsetAsync(z, 0, sizeof(float) * NGRAPHS * ZSTR, stream);
    dim3 pgrid(NGRAPHS, NSLICE);
    pool_partial<<<pgrid, HID, 0, stream>>>(h, gstart, z);
    pool_finalize<<<NGRAPHS, HID, 0, stream>>>(gstart, hlr, stdv, z);
    fc_k<<<NGRAPHS, HID, 0, stream>>>(z, fcW0, fcb0, fcW1, fcb1, out);
}